// Round 6
// baseline (203.995 us; speedup 1.0000x reference)
//
#include <hip/hip_runtime.h>

// Dynamic range compressor via composed piecewise-linear scan operators.
//   gr[t]  = max(20*log10(|x|+1e-8) - thr, 0)*(1-1/ratio)
//   g[0]=0; g[t] = (1-a)*g[t-1] + a*gr[t],  a = att if gr[t]>g[t-1] else rel
//   out[t] = sign(x)*(|x|+1e-8)*10^((mk - g[t])/20)
// Per-sample update = max of two affine fns of g; max-affine ops compose
// exactly (slopes b1^k*b2^(m-k), m+1 classes). Each 4-sample block is EXACTLY
// g' = max_{k=0..4}(I_k + S_k*g); intercepts precomputed fp16 (pre_kernel).
// Chunked scan, C=512, W=12288 warm-up (contraction; error at bf16 floor).
// Round 6 (from r5 counters: 1 wave/CU, VALUBusy 13%, ~170cyc naked stall per
// record): C=1024->512 (2 waves/CU TLP) + depth-8 modulo pipeline on records
// (prefetch 7, ~35 loads in flight) to cover L2/HBM latency.
// NOTE: no <math.h> (glibc __MATHCALL collides with HIP intrinsics).

#define T_LEN   (1 << 20)
#define W_WARM  12288
#define C_CHUNK 512
#define RECS_PER_CH (T_LEN / 32)   // 32768 records (32 samples each) per channel

typedef _Float16 half_t;
typedef _Float16 half8 __attribute__((ext_vector_type(8)));
typedef float    fvec4 __attribute__((ext_vector_type(4)));

__device__ __forceinline__ float fmax3f(float a, float b, float c) {
  return fmaxf(fmaxf(a, b), c);   // clang fuses to v_max3_f32
}

// One thread per 32-sample record: compute gr, compose pairs->quads, store
// 5 half8 per record; h[j][q] = intercept class j (slope S_j) of quad q.
__global__ __launch_bounds__(256) void pre_kernel(
    const float* __restrict__ audio,
    const float* __restrict__ p_thr,
    const float* __restrict__ p_ratio,
    const float* __restrict__ p_att,
    const float* __restrict__ p_rel,
    half8* __restrict__ recs, int nrec_total) {
  int rec = blockIdx.x * blockDim.x + threadIdx.x;
  if (rec >= nrec_total) return;
  const float thr = p_thr[0];
  const float r1  = 1.0f - 1.0f / p_ratio[0];
  const float K   = 6.0205999132796239f * r1;    // 20*log10(2)*r1
  const float Cc  = -thr * r1;
  const float L2E = 1.4426950408889634f;
  const float aatt = 1.0f - __builtin_exp2f(-L2E / (p_att[0] * 48000.0f));
  const float arel = 1.0f - __builtin_exp2f(-L2E / (p_rel[0] * 48000.0f));
  const float b1 = 1.0f - aatt, b2 = 1.0f - arel;
  const float s0 = b1 * b1, s1 = b1 * b2, s2 = b2 * b2;

  const fvec4* A4 = (const fvec4*)(audio) + (size_t)rec * 8;
  float gr[32];
#pragma unroll
  for (int i = 0; i < 8; ++i) {
    fvec4 v = A4[i];
#pragma unroll
    for (int j = 0; j < 4; ++j)
      gr[4 * i + j] =
          fmaxf(fmaf(K, __builtin_log2f(fabsf(v[j]) + 1e-8f), Cc), 0.0f);
  }
  if ((rec & (RECS_PER_CH - 1)) == 0) gr[0] = 0.0f;  // t==0: scan makes no update

  half8 h[5];
#pragma unroll
  for (int q = 0; q < 8; ++q) {
    // pair (4q,4q+1): att line (A,b1), rel line (R,b2); outer sample is later.
    float A0 = aatt * gr[4*q],     R0 = arel * gr[4*q];
    float A1 = aatt * gr[4*q + 1], R1 = arel * gr[4*q + 1];
    float u0 = fmaf(b1, A0, A1);                               // slope s0
    float um = fmaxf(fmaf(b1, R0, A1), fmaf(b2, A0, R1));      // slope s1
    float u2 = fmaf(b2, R0, R1);                               // slope s2
    float A2 = aatt * gr[4*q + 2], R2 = arel * gr[4*q + 2];
    float A3 = aatt * gr[4*q + 3], R3 = arel * gr[4*q + 3];
    float v0 = fmaf(b1, A2, A3);
    float vm = fmaxf(fmaf(b1, R2, A3), fmaf(b2, A2, R3));
    float v2 = fmaf(b2, R2, R3);
    // quad = vpair ∘ upair : w_k = max_{i+j=k}(v_i + s_i*u_j)
    float w0 = fmaf(s0, u0, v0);
    float w1 = fmaxf(fmaf(s0, um, v0), fmaf(s1, u0, vm));
    float w2 = fmax3f(fmaf(s0, u2, v0), fmaf(s1, um, vm), fmaf(s2, u0, v2));
    float w3 = fmaxf(fmaf(s1, u2, vm), fmaf(s2, um, v2));
    float w4 = fmaf(s2, u2, v2);
    h[0][q] = (half_t)w0; h[1][q] = (half_t)w1; h[2][q] = (half_t)w2;
    h[3][q] = (half_t)w3; h[4][q] = (half_t)w4;
  }
  half8* dst = recs + (size_t)rec * 5;
#pragma unroll
  for (int j = 0; j < 5; ++j) dst[j] = h[j];
}

__global__ __launch_bounds__(64) void comp_kernel(
    const float* __restrict__ audio,
    const half8* __restrict__ recs,
    const float* __restrict__ p_thr,
    const float* __restrict__ p_ratio,
    const float* __restrict__ p_att,
    const float* __restrict__ p_rel,
    const float* __restrict__ p_mk,
    float* __restrict__ out, int total_chunks) {
  const int tid = blockIdx.x * blockDim.x + threadIdx.x;
  if (tid >= total_chunks) return;
  const int CPC = T_LEN / C_CHUNK;
  const int ch = tid / CPC;
  const int t0 = (tid - ch * CPC) * C_CHUNK;

  const float thr = p_thr[0];
  const float r1  = 1.0f - 1.0f / p_ratio[0];
  const float K   = 6.0205999132796239f * r1;
  const float Cc  = -thr * r1;
  const float L2E = 1.4426950408889634f;
  const float aatt = 1.0f - __builtin_exp2f(-L2E / (p_att[0] * 48000.0f));
  const float arel = 1.0f - __builtin_exp2f(-L2E / (p_rel[0] * 48000.0f));
  const float b1 = 1.0f - aatt, b2 = 1.0f - arel;
  const float s0 = b1 * b1, s1 = b1 * b2, s2 = b2 * b2;
  const float S0 = s0 * s0, S1 = s0 * s1, S2 = s1 * s1, S3 = s1 * s2, S4 = s2 * s2;
  const float EK  = 0.16609640474436813f;       // log2(10)/20
  const float emk = p_mk[0] * EK;

  float g = 0.0f;

  // ---- Warm-up: composed quad steps, depth-8 modulo pipeline over records.
  int start = t0 - W_WARM;
  if (start < 0) start = 0;
  const int nrec = (t0 - start) >> 5;   // multiple of 16 (W/32=384, C/32=16)
  if (nrec > 0) {
    const half8* P = recs + ((size_t)ch * RECS_PER_CH + (start >> 5)) * 5;
    half8 buf[8][5];                     // static-indexed only (no scratch)
#define LD(slot, r)                                                     \
  {                                                                     \
    const half8* p = P + 5 * (r);                                       \
    _Pragma("unroll") for (int i = 0; i < 5; ++i) buf[slot][i] = p[i];  \
  }
    auto proc = [&](const half8 (&b)[5]) {
#pragma unroll
      for (int q = 0; q < 8; ++q) {
        float l0 = fmaf(S0, g, (float)b[0][q]);
        float l1 = fmaf(S1, g, (float)b[1][q]);
        float l2 = fmaf(S2, g, (float)b[2][q]);
        float l3 = fmaf(S3, g, (float)b[3][q]);
        float l4 = fmaf(S4, g, (float)b[4][q]);
        g = fmax3f(fmax3f(l0, l1, l2), l3, l4);
      }
    };
    LD(0, 0) LD(1, 1) LD(2, 2) LD(3, 3) LD(4, 4) LD(5, 5) LD(6, 6)
#pragma unroll 1
    for (int r = 0; r + 8 <= nrec; r += 8) {
      // overrun loads reach <= record (t0>>5)+6 < RECS_PER_CH: in-bounds, unused
      LD(7, r + 7)  proc(buf[0]);
      LD(0, r + 8)  proc(buf[1]);
      LD(1, r + 9)  proc(buf[2]);
      LD(2, r + 10) proc(buf[3]);
      LD(3, r + 11) proc(buf[4]);
      LD(4, r + 12) proc(buf[5]);
      LD(5, r + 13) proc(buf[6]);
      LD(6, r + 14) proc(buf[7]);
    }
#undef LD
  }

  // ---- Output region: per-sample, gr computed inline from audio. ----
  const fvec4* Ap = (const fvec4*)(audio + (size_t)ch * T_LEN + t0);
  fvec4* Op = (fvec4*)(out + (size_t)ch * T_LEN + t0);
  const bool zfix = (t0 == 0);

  fvec4 a0[8], a1[8];
  auto lda = [&](fvec4 (&ab)[8], int b) {
#pragma unroll
    for (int i = 0; i < 8; ++i) ab[i] = Ap[8 * b + i];
  };
  auto emit = [&](const fvec4 (&ab)[8], int b, bool first) {
    fvec4 r[8];
#pragma unroll
    for (int s = 0; s < 32; ++s) {
      float x = ab[s >> 2][s & 3];
      float ax = fabsf(x) + 1e-8f;
      float grv = fmaxf(fmaf(K, __builtin_log2f(ax), Cc), 0.0f);
      if (first && s == 0 && zfix) grv = 0.0f;   // t==0: g stays 0
      float d = grv - g;
      g = fmaxf(fmaf(aatt, d, g), fmaf(arel, d, g));
      float mag = ax * __builtin_exp2f(fmaf(-EK, g, emk));
      float o = copysignf(mag, x);
      r[s >> 2][s & 3] = (x == 0.0f) ? 0.0f : o;
    }
#pragma unroll
    for (int i = 0; i < 8; ++i) Op[8 * b + i] = r[i];
  };

  const int NB = C_CHUNK / 32;     // 16 blocks
  lda(a0, 0);
#pragma unroll 1
  for (int b = 0; b < NB; b += 2) {
    lda(a1, b + 1);
    emit(a0, b, b == 0);
    int b2 = (b + 2 < NB) ? b + 2 : NB - 1;      // clamp: no OOB at channel end
    lda(a0, b2);
    emit(a1, b + 1, false);
  }
}

extern "C" void kernel_launch(void* const* d_in, const int* in_sizes, int n_in,
                              void* d_out, int out_size, void* d_ws, size_t ws_size,
                              hipStream_t stream) {
  const float* audio   = (const float*)d_in[0];
  const float* p_thr   = (const float*)d_in[1];
  const float* p_ratio = (const float*)d_in[2];
  const float* p_att   = (const float*)d_in[3];
  const float* p_rel   = (const float*)d_in[4];
  const float* p_mk    = (const float*)d_in[5];
  float* outp = (float*)d_out;

  const int n = in_sizes[0];                 // 16 * 2^20
  const int nrec_total = n / 32;             // 524288 records, 80 B each = 42 MB
  const int total_chunks = n / C_CHUNK;      // 32768
  half8* recs = (half8*)d_ws;                // fits: ws_size >= 64 MB

  pre_kernel<<<(nrec_total + 255) / 256, 256, 0, stream>>>(
      audio, p_thr, p_ratio, p_att, p_rel, recs, nrec_total);
  comp_kernel<<<(total_chunks + 63) / 64, 64, 0, stream>>>(
      audio, recs, p_thr, p_ratio, p_att, p_rel, p_mk, outp, total_chunks);
}

// Round 7
// 171.389 us; speedup vs baseline: 1.1902x; 1.1902x over previous
//
#include <hip/hip_runtime.h>

// Dynamic range compressor via composed piecewise-linear scan operators.
//   gr[t]  = max(20*log10(|x|+1e-8) - thr, 0)*(1-1/ratio)
//   g[0]=0; g[t] = (1-a)*g[t-1] + a*gr[t],  a = att if gr[t]>g[t-1] else rel
//   out[t] = sign(x)*(|x|+1e-8)*10^((mk - g[t])/20)
// Per-sample update = max of two affine fns of g; max-affine ops compose
// exactly (max-plus convolution of intercepts; slope classes b1^(m-k)*b2^k).
// pre_kernel now composes each 32-sample record FULLY into its exact
// 33-piece operator (5->9->17->33). comp warm-up = ONE apply per record:
// 33 fma + max tree (chain ~5 ops vs 24 for 8 serial quads).
// Round 7 fixes from r6 counters: (a) VGPR_Count=48 proved the compiler
// pressure-scheduled the prefetch ring away -> __launch_bounds__(64,1);
// (b) FETCH 479MB L2 thrash -> C=1024 (half traffic) + XCD-chunked wg
// swizzle (record-sharing threads colocate per XCD); (c) W=12288->8192.
// NOTE: no <math.h> (glibc __MATHCALL collides with HIP intrinsics).

#define T_LEN   (1 << 20)
#define W_WARM  8192
#define C_CHUNK 1024
#define RECS_PER_CH (T_LEN / 32)   // 32768 records (32 samples each) per channel

typedef _Float16 half_t;
typedef _Float16 half8 __attribute__((ext_vector_type(8)));
typedef float    fvec4 __attribute__((ext_vector_type(4)));

__device__ __forceinline__ float fmax3f(float a, float b, float c) {
  return fmaxf(fmaxf(a, b), c);   // clang fuses to v_max3_f32
}

// Compose: dst = hi ∘ lo (hi applied AFTER lo). P,Q = piece counts.
// Convention: piece index k = number of RELEASE steps; slope(m,k)=b1^(m-k)b2^k.
// shi[i] = slope of hi's piece i. dst[k] = max_{i+j=k}(hi[i] + shi[i]*lo[j]).
template <int P, int Q>
__device__ __forceinline__ void compose(float* __restrict__ dst,
                                        const float* __restrict__ hi,
                                        const float* __restrict__ lo,
                                        const float* __restrict__ shi) {
#pragma unroll
  for (int k = 0; k < P + Q - 1; ++k) {
    float m = -1e30f;
#pragma unroll
    for (int i = 0; i < P; ++i) {
      const int j = k - i;
      if (j >= 0 && j < Q) m = fmaxf(m, fmaf(shi[i], lo[j], hi[i]));
    }
    dst[k] = m;
  }
}

// One thread per 32-sample record: gr -> 8 quads -> 4x9 -> 2x17 -> 1x33.
// Store 33 intercepts (fp16) + 7 pad = 5 half8 = 80 B per record.
__global__ __launch_bounds__(256) void pre_kernel(
    const float* __restrict__ audio,
    const float* __restrict__ p_thr,
    const float* __restrict__ p_ratio,
    const float* __restrict__ p_att,
    const float* __restrict__ p_rel,
    half8* __restrict__ recs, int nrec_total) {
  int rec = blockIdx.x * blockDim.x + threadIdx.x;
  if (rec >= nrec_total) return;
  const float thr = p_thr[0];
  const float r1  = 1.0f - 1.0f / p_ratio[0];
  const float K   = 6.0205999132796239f * r1;    // 20*log10(2)*r1
  const float Cc  = -thr * r1;
  const float L2E = 1.4426950408889634f;
  const float aatt = 1.0f - __builtin_exp2f(-L2E / (p_att[0] * 48000.0f));
  const float arel = 1.0f - __builtin_exp2f(-L2E / (p_rel[0] * 48000.0f));
  const float b1 = 1.0f - aatt, b2 = 1.0f - arel;
  const float s0 = b1 * b1, s1 = b1 * b2, s2 = b2 * b2;
  const float rat = b2 / b1;

  // slope tables: s4[i]=b1^(4-i)b2^i, s8, s16
  float s4[5], s8[9], s16[17];
  {
    const float b1_2 = b1 * b1, b1_4 = b1_2 * b1_2, b1_8 = b1_4 * b1_4;
    float p = b1_4;
#pragma unroll
    for (int i = 0; i < 5; ++i) { s4[i] = p; p *= rat; }
    p = b1_8;
#pragma unroll
    for (int i = 0; i < 9; ++i) { s8[i] = p; p *= rat; }
    p = b1_8 * b1_8;
#pragma unroll
    for (int i = 0; i < 17; ++i) { s16[i] = p; p *= rat; }
  }

  const fvec4* A4 = (const fvec4*)(audio) + (size_t)rec * 8;
  float gr[32];
#pragma unroll
  for (int i = 0; i < 8; ++i) {
    fvec4 v = A4[i];
#pragma unroll
    for (int j = 0; j < 4; ++j)
      gr[4 * i + j] =
          fmaxf(fmaf(K, __builtin_log2f(fabsf(v[j]) + 1e-8f), Cc), 0.0f);
  }
  if ((rec & (RECS_PER_CH - 1)) == 0) gr[0] = 0.0f;  // t==0: scan makes no update

  // quads: q[b][k], k=0 all-attack (slope b1^4) .. k=4 all-release
  float q[8][5];
#pragma unroll
  for (int b = 0; b < 8; ++b) {
    float A0 = aatt * gr[4*b],     R0 = arel * gr[4*b];
    float A1 = aatt * gr[4*b + 1], R1 = arel * gr[4*b + 1];
    float u0 = fmaf(b1, A0, A1);                              // slope b1^2
    float um = fmaxf(fmaf(b1, R0, A1), fmaf(b2, A0, R1));     // b1 b2
    float u2 = fmaf(b2, R0, R1);                              // b2^2
    float A2 = aatt * gr[4*b + 2], R2 = arel * gr[4*b + 2];
    float A3 = aatt * gr[4*b + 3], R3 = arel * gr[4*b + 3];
    float v0 = fmaf(b1, A2, A3);
    float vm = fmaxf(fmaf(b1, R2, A3), fmaf(b2, A2, R3));
    float v2 = fmaf(b2, R2, R3);
    q[b][0] = fmaf(s0, u0, v0);
    q[b][1] = fmaxf(fmaf(s0, um, v0), fmaf(s1, u0, vm));
    q[b][2] = fmax3f(fmaf(s0, u2, v0), fmaf(s1, um, vm), fmaf(s2, u0, v2));
    q[b][3] = fmaxf(fmaf(s1, u2, vm), fmaf(s2, um, v2));
    q[b][4] = fmaf(s2, u2, v2);
  }

  float o9a[9], o9b[9], o17a[17], o17b[17], o33[33];
  compose<5, 5>(o9a, q[1], q[0], s4);
  compose<5, 5>(o9b, q[3], q[2], s4);
  compose<9, 9>(o17a, o9b, o9a, s8);
  compose<5, 5>(o9a, q[5], q[4], s4);
  compose<5, 5>(o9b, q[7], q[6], s4);
  compose<9, 9>(o17b, o9b, o9a, s8);
  compose<17, 17>(o33, o17b, o17a, s16);

  half8 hh[5];
#pragma unroll
  for (int j = 0; j < 5; ++j)
#pragma unroll
    for (int e = 0; e < 8; ++e) {
      const int idx = 8 * j + e;
      hh[j][e] = (idx < 33) ? (half_t)o33[idx] : (half_t)0.0f;
    }
  half8* dst = recs + (size_t)rec * 5;
#pragma unroll
  for (int j = 0; j < 5; ++j) dst[j] = hh[j];
}

__global__ __launch_bounds__(64, 1) void comp_kernel(
    const float* __restrict__ audio,
    const half8* __restrict__ recs,
    const float* __restrict__ p_thr,
    const float* __restrict__ p_ratio,
    const float* __restrict__ p_att,
    const float* __restrict__ p_rel,
    const float* __restrict__ p_mk,
    float* __restrict__ out, int total_chunks) {
  // XCD-chunked swizzle: give each XCD a contiguous block of workgroups so
  // threads sharing record windows hit the same L2. nwg must be %8==0 (256).
  const int nwg = gridDim.x;
  const int cpx = nwg >> 3;
  const int w = blockIdx.x;
  const int sw = (w & 7) * cpx + (w >> 3);
  const int tid = sw * 64 + (int)threadIdx.x;
  if (tid >= total_chunks) return;
  const int CPC = T_LEN / C_CHUNK;
  const int ch = tid / CPC;
  const int t0 = (tid - ch * CPC) * C_CHUNK;

  const float thr = p_thr[0];
  const float r1  = 1.0f - 1.0f / p_ratio[0];
  const float K   = 6.0205999132796239f * r1;
  const float Cc  = -thr * r1;
  const float L2E = 1.4426950408889634f;
  const float aatt = 1.0f - __builtin_exp2f(-L2E / (p_att[0] * 48000.0f));
  const float arel = 1.0f - __builtin_exp2f(-L2E / (p_rel[0] * 48000.0f));
  const float b1 = 1.0f - aatt, b2 = 1.0f - arel;
  const float EK  = 0.16609640474436813f;       // log2(10)/20
  const float emk = p_mk[0] * EK;

  // S32[k] = b1^(32-k) * b2^k, k=0..32
  float S32[33];
  {
    const float b1_2 = b1 * b1, b1_4 = b1_2 * b1_2, b1_8 = b1_4 * b1_4;
    const float b1_16 = b1_8 * b1_8;
    const float rat = b2 / b1;
    float p = b1_16 * b1_16;
#pragma unroll
    for (int i = 0; i < 33; ++i) { S32[i] = p; p *= rat; }
  }

  float g = 0.0f;

  // ---- Warm-up: one 33-piece apply per record, depth-8 modulo pipeline.
  int start = t0 - W_WARM;
  if (start < 0) start = 0;
  const int nrec = (t0 - start) >> 5;   // multiple of 32 (W/32=256, C/32=32)
  if (nrec > 0) {
    const half8* P = recs + ((size_t)ch * RECS_PER_CH + (start >> 5)) * 5;
    half8 buf[8][5];                     // static-indexed only (no scratch)
#define LD(slot, r)                                                     \
  {                                                                     \
    const half8* p_ = P + 5 * (r);                                      \
    _Pragma("unroll") for (int i = 0; i < 5; ++i) buf[slot][i] = p_[i]; \
  }
    auto proc = [&](const half8 (&b)[5]) {
      float l[33];
#pragma unroll
      for (int k = 0; k < 33; ++k)
        l[k] = fmaf(S32[k], g, (float)b[k >> 3][k & 7]);
      float m[11];
#pragma unroll
      for (int t = 0; t < 11; ++t) m[t] = fmax3f(l[3*t], l[3*t+1], l[3*t+2]);
      float u0 = fmax3f(m[0], m[1], m[2]);
      float u1 = fmax3f(m[3], m[4], m[5]);
      float u2 = fmax3f(m[6], m[7], m[8]);
      float u3 = fmaxf(m[9], m[10]);
      g = fmaxf(fmax3f(u0, u1, u2), u3);
    };
    LD(0, 0) LD(1, 1) LD(2, 2) LD(3, 3) LD(4, 4) LD(5, 5) LD(6, 6)
#pragma unroll 1
    for (int r = 0; r + 8 <= nrec; r += 8) {
      // overrun loads reach <= record (t0>>5)+6 < RECS_PER_CH: in-bounds, unused
      LD(7, r + 7)  proc(buf[0]);
      LD(0, r + 8)  proc(buf[1]);
      LD(1, r + 9)  proc(buf[2]);
      LD(2, r + 10) proc(buf[3]);
      LD(3, r + 11) proc(buf[4]);
      LD(4, r + 12) proc(buf[5]);
      LD(5, r + 13) proc(buf[6]);
      LD(6, r + 14) proc(buf[7]);
    }
#undef LD
  }

  // ---- Output region: per-sample, gr computed inline from audio. ----
  const fvec4* Ap = (const fvec4*)(audio + (size_t)ch * T_LEN + t0);
  fvec4* Op = (fvec4*)(out + (size_t)ch * T_LEN + t0);
  const bool zfix = (t0 == 0);

  fvec4 a0[8], a1[8];
  auto lda = [&](fvec4 (&ab)[8], int b) {
#pragma unroll
    for (int i = 0; i < 8; ++i) ab[i] = Ap[8 * b + i];
  };
  auto emit = [&](const fvec4 (&ab)[8], int b, bool first) {
    fvec4 r[8];
#pragma unroll
    for (int s = 0; s < 32; ++s) {
      float x = ab[s >> 2][s & 3];
      float ax = fabsf(x) + 1e-8f;
      float grv = fmaxf(fmaf(K, __builtin_log2f(ax), Cc), 0.0f);
      if (first && s == 0 && zfix) grv = 0.0f;   // t==0: g stays 0
      float d = grv - g;
      g = fmaxf(fmaf(aatt, d, g), fmaf(arel, d, g));
      float mag = ax * __builtin_exp2f(fmaf(-EK, g, emk));
      float o = copysignf(mag, x);
      r[s >> 2][s & 3] = (x == 0.0f) ? 0.0f : o;
    }
#pragma unroll
    for (int i = 0; i < 8; ++i) Op[8 * b + i] = r[i];
  };

  const int NB = C_CHUNK / 32;     // 32 blocks
  lda(a0, 0);
#pragma unroll 1
  for (int b = 0; b < NB; b += 2) {
    lda(a1, b + 1);
    emit(a0, b, b == 0);
    int b2 = (b + 2 < NB) ? b + 2 : NB - 1;      // clamp: no OOB at channel end
    lda(a0, b2);
    emit(a1, b + 1, false);
  }
}

extern "C" void kernel_launch(void* const* d_in, const int* in_sizes, int n_in,
                              void* d_out, int out_size, void* d_ws, size_t ws_size,
                              hipStream_t stream) {
  const float* audio   = (const float*)d_in[0];
  const float* p_thr   = (const float*)d_in[1];
  const float* p_ratio = (const float*)d_in[2];
  const float* p_att   = (const float*)d_in[3];
  const float* p_rel   = (const float*)d_in[4];
  const float* p_mk    = (const float*)d_in[5];
  float* outp = (float*)d_out;

  const int n = in_sizes[0];                 // 16 * 2^20
  const int nrec_total = n / 32;             // 524288 records, 80 B each = 42 MB
  const int total_chunks = n / C_CHUNK;      // 16384
  half8* recs = (half8*)d_ws;                // fits: ws_size >= 64 MB

  pre_kernel<<<(nrec_total + 255) / 256, 256, 0, stream>>>(
      audio, p_thr, p_ratio, p_att, p_rel, recs, nrec_total);
  comp_kernel<<<(total_chunks + 63) / 64, 64, 0, stream>>>(
      audio, recs, p_thr, p_ratio, p_att, p_rel, p_mk, outp, total_chunks);
}